// Round 3
// baseline (5149.309 us; speedup 1.0000x reference)
//
#include <hip/hip_runtime.h>
#include <math.h>

#define HH 128
#define WW 128
#define NPIX 16384
#define CIN 3
#define DD 32
#define QQ 128
#define MM 16
#define NBATCH 2
#define EPSF 1e-8f

// ---------------- conv1: 3x3, 3->32, relu, zero-pad SAME ----------------
__global__ __launch_bounds__(256) void conv1_kernel(
    const float* __restrict__ x, const float* __restrict__ w1,
    const float* __restrict__ b1, float* __restrict__ out)
{
    __shared__ float wlds[9 * CIN * DD];
    int t = threadIdx.x;
    for (int idx = t; idx < 9 * CIN * DD / 4; idx += 256)
        ((float4*)wlds)[idx] = ((const float4*)w1)[idx];
    __syncthreads();

    int ocq = t & 3;
    int pl  = t >> 2;
    int blk = blockIdx.x;                   // 512
    int b   = blk >> 8;
    int pix = (blk & 255) * 64 + pl;
    int i = pix >> 7, j = pix & 127;
    int ocb = ocq << 3;

    float4 acc0 = *(const float4*)(b1 + ocb);
    float4 acc1 = *(const float4*)(b1 + ocb + 4);
    #pragma unroll
    for (int dy = 0; dy < 3; dy++) {
        int ii = i + dy - 1;
        if (ii < 0 || ii >= HH) continue;
        #pragma unroll
        for (int dx = 0; dx < 3; dx++) {
            int jj = j + dx - 1;
            if (jj < 0 || jj >= WW) continue;
            const float* fr = x + ((size_t)((b << 14) + ii * WW + jj)) * CIN;
            float in0 = fr[0], in1 = fr[1], in2 = fr[2];
            const float* wp = wlds + (size_t)((dy * 3 + dx) * CIN) * DD + ocb;
            #pragma unroll
            for (int ic = 0; ic < 3; ic++) {
                float inv = (ic == 0) ? in0 : (ic == 1) ? in1 : in2;
                float4 w0 = *(const float4*)(wp + ic * DD);
                float4 w1v = *(const float4*)(wp + ic * DD + 4);
                acc0.x += inv * w0.x;  acc0.y += inv * w0.y;
                acc0.z += inv * w0.z;  acc0.w += inv * w0.w;
                acc1.x += inv * w1v.x; acc1.y += inv * w1v.y;
                acc1.z += inv * w1v.z; acc1.w += inv * w1v.w;
            }
        }
    }
    float* op = out + (((size_t)(b << 14) + pix) << 5) + ocb;
    float4 r0 = {fmaxf(acc0.x, 0.f), fmaxf(acc0.y, 0.f), fmaxf(acc0.z, 0.f), fmaxf(acc0.w, 0.f)};
    float4 r1 = {fmaxf(acc1.x, 0.f), fmaxf(acc1.y, 0.f), fmaxf(acc1.z, 0.f), fmaxf(acc1.w, 0.f)};
    *(float4*)op = r0;
    *(float4*)(op + 4) = r1;
}

// ---------------- conv2: 3x3, 32->32, relu ----------------
__global__ __launch_bounds__(256) void conv2_kernel(
    const float* __restrict__ fin, const float* __restrict__ w2,
    const float* __restrict__ b2, float* __restrict__ out)
{
    __shared__ float wlds[9 * DD * DD];    // 36.9 KB
    int t = threadIdx.x;
    for (int idx = t; idx < 9 * DD * DD / 4; idx += 256)
        ((float4*)wlds)[idx] = ((const float4*)w2)[idx];
    __syncthreads();

    int ocq = t & 3;
    int pl  = t >> 2;
    int blk = blockIdx.x;                   // 512
    int b   = blk >> 8;
    int pix = (blk & 255) * 64 + pl;
    int i = pix >> 7, j = pix & 127;
    int ocb = ocq << 3;

    float4 acc0 = *(const float4*)(b2 + ocb);
    float4 acc1 = *(const float4*)(b2 + ocb + 4);
    #pragma unroll
    for (int dy = 0; dy < 3; dy++) {
        int ii = i + dy - 1;
        if (ii < 0 || ii >= HH) continue;
        #pragma unroll
        for (int dx = 0; dx < 3; dx++) {
            int jj = j + dx - 1;
            if (jj < 0 || jj >= WW) continue;
            const float* fr = fin + (((size_t)(b << 14) + ii * WW + jj)) * DD;
            float iv[DD];
            #pragma unroll
            for (int c = 0; c < DD / 4; c++)
                ((float4*)iv)[c] = *(const float4*)(fr + c * 4);
            const float* wp = wlds + (size_t)((dy * 3 + dx) * DD) * DD + ocb;
            #pragma unroll
            for (int ic = 0; ic < DD; ic++) {
                float inv = iv[ic];
                float4 w0 = *(const float4*)(wp + ic * DD);
                float4 w1v = *(const float4*)(wp + ic * DD + 4);
                acc0.x += inv * w0.x;  acc0.y += inv * w0.y;
                acc0.z += inv * w0.z;  acc0.w += inv * w0.w;
                acc1.x += inv * w1v.x; acc1.y += inv * w1v.y;
                acc1.z += inv * w1v.z; acc1.w += inv * w1v.w;
            }
        }
    }
    float* op = out + (((size_t)(b << 14) + pix) << 5) + ocb;
    float4 r0 = {fmaxf(acc0.x, 0.f), fmaxf(acc0.y, 0.f), fmaxf(acc0.z, 0.f), fmaxf(acc0.w, 0.f)};
    float4 r1 = {fmaxf(acc1.x, 0.f), fmaxf(acc1.y, 0.f), fmaxf(acc1.z, 0.f), fmaxf(acc1.w, 0.f)};
    *(float4*)op = r0;
    *(float4*)(op + 4) = r1;
}

// ---------------- k/q 1x1 projections + row norms ----------------
__global__ __launch_bounds__(256) void kq_kernel(
    const float* __restrict__ fin, const float* __restrict__ wk,
    const float* __restrict__ bk, const float* __restrict__ wq,
    float* __restrict__ ksb, float* __restrict__ qsb,
    float* __restrict__ knorm, float* __restrict__ qnorm)
{
    int g  = blockIdx.x * 256 + threadIdx.x;  // B*N*32
    int oc = g & 31;
    int bp = g >> 5;
    const float* fr = fin + (size_t)bp * DD;
    float ak = bk[oc], aq = 0.0f;
    #pragma unroll
    for (int ic = 0; ic < DD; ic += 4) {
        float4 fv = *(const float4*)(fr + ic);
        ak += fv.x * wk[(ic + 0) * DD + oc];
        ak += fv.y * wk[(ic + 1) * DD + oc];
        ak += fv.z * wk[(ic + 2) * DD + oc];
        ak += fv.w * wk[(ic + 3) * DD + oc];
        aq += fv.x * wq[(ic + 0) * DD + oc];
        aq += fv.y * wq[(ic + 1) * DD + oc];
        aq += fv.z * wq[(ic + 2) * DD + oc];
        aq += fv.w * wq[(ic + 3) * DD + oc];
    }
    ksb[g] = ak;
    qsb[g] = aq;
    float ssk = ak * ak, ssq = aq * aq;
    #pragma unroll
    for (int m = 1; m < 32; m <<= 1) {
        ssk += __shfl_xor(ssk, m, 64);
        ssq += __shfl_xor(ssq, m, 64);
    }
    if (oc == 0) {
        knorm[bp] = sqrtf(ssk);
        qnorm[bp] = sqrtf(ssq);
    }
}

// ---------------- edge scores: LDS-tiled exp(cosine) + per-batch sums ----
__global__ __launch_bounds__(256) void edge_kernel(
    const float* __restrict__ ksb, const float* __restrict__ qsb,
    const float* __restrict__ knorm, const float* __restrict__ qnorm,
    float* __restrict__ wT, float* __restrict__ sums)
{
    __shared__ float kt[144][36];   // +4 pad: breaks 32-stride bank aliasing
    __shared__ float qt[64][36];
    __shared__ float kn[144];
    __shared__ float qn[64];
    __shared__ float red[4];
    const int t   = threadIdx.x;
    const int blk = blockIdx.x;     // 512
    const int b   = blk >> 8;
    const int tl  = blk & 255;
    const int ti0 = (tl >> 4) << 3, tj0 = (tl & 15) << 3;
    const float* kb = ksb + ((size_t)b << 19);
    const float* qb = qsb + ((size_t)b << 19);

    for (int idx = t; idx < 144 * 8; idx += 256) {
        int row = idx >> 3, quad = idx & 7;
        int ar = row / 12, ac = row - ar * 12;
        int gi = min(max(ti0 + ar - 2, 0), HH - 1);
        int gj = min(max(tj0 + ac - 2, 0), WW - 1);
        *(float4*)&kt[row][quad << 2] =
            *(const float4*)(kb + ((size_t)(gi * WW + gj) << 5) + (quad << 2));
    }
    for (int idx = t; idx < 64 * 8; idx += 256) {
        int row = idx >> 3, quad = idx & 7;
        int gp = (ti0 + (row >> 3)) * WW + tj0 + (row & 7);
        *(float4*)&qt[row][quad << 2] =
            *(const float4*)(qb + ((size_t)gp << 5) + (quad << 2));
    }
    if (t < 144) {
        int ar = t / 12, ac = t - ar * 12;
        int gi = min(max(ti0 + ar - 2, 0), HH - 1);
        int gj = min(max(tj0 + ac - 2, 0), WW - 1);
        kn[t] = knorm[(b << 14) + gi * WW + gj];
    } else if (t < 208) {
        int r2 = t - 144;
        int gp = (ti0 + (r2 >> 3)) * WW + tj0 + (r2 & 7);
        qn[r2] = qnorm[(b << 14) + gp];
    }
    __syncthreads();

    const int nl = t >> 2, s = t & 3;
    const int p = nl >> 3, q = nl & 7;
    float4 qv[8];
    #pragma unroll
    for (int c = 0; c < 8; c++) qv[c] = *(const float4*)&qt[nl][c << 2];
    const float qnv = qn[nl];
    const int gp = (ti0 + p) * WW + tj0 + q;
    float* wrow = wT + (((size_t)(b << 14) + gp) << 5);
    float lsum = 0.0f;
    for (int o = s; o < 25; o += 4) {
        int di = o / 5, dj = o - di * 5;      // 0..4
        int krow = (p + di) * 12 + (q + dj);  // halo coords
        const float* kr = &kt[krow][0];
        float dot = 0.0f;
        #pragma unroll
        for (int c = 0; c < 8; c++) {
            float4 kv = *(const float4*)(kr + (c << 2));
            dot += qv[c].x * kv.x + qv[c].y * kv.y + qv[c].z * kv.z + qv[c].w * kv.w;
        }
        float den = fmaxf(qnv * kn[krow], EPSF);
        float es = expf(dot / den);   // cosine in [-1,1]: no max-sub needed
        wrow[o] = es;
        lsum += es;
    }
    #pragma unroll
    for (int mm = 1; mm < 64; mm <<= 1) lsum += __shfl_xor(lsum, mm, 64);
    if ((t & 63) == 0) red[t >> 6] = lsum;
    __syncthreads();
    if (t == 0) atomicAdd(&sums[b], red[0] + red[1] + red[2] + red[3]);
}

// ---------------- fused propagation: all 32 iterations, persistent -------
// Plain (graph-capture-safe) launch; manual device-scope atomic barrier.
// Co-residency by construction: 512 blocks = 256 CU x 2; launch_bounds
// (256,2) caps VGPR<=256; LDS 48.4 KB -> 3 blocks/CU. Monotonic counter
// barrier (memset per launch), agent-scope fences for cross-XCD L2
// visibility, bounded spin as anti-hang failsafe.
__global__ __launch_bounds__(256, 2) void prop_fused_kernel(
    const float* __restrict__ hinit, float* __restrict__ hA,
    float* __restrict__ hB, const float* __restrict__ wT,
    const float* __restrict__ sums, unsigned int* bar)
{
    __shared__ float4 tile_s[144 * 17];    // 12x12 pixels x 16 slots, pad 17
    __shared__ float wts[64][36];          // pre-scaled softmax weights

    const int t = threadIdx.x;
    const int x = blockIdx.x & 7;          // XCD slab heuristic
    const int r = blockIdx.x >> 3;         // 0..63 within slab
    const int g_tr = (x << 2) + (r >> 4);  // global tile-row 0..31
    const int b   = g_tr >> 4;
    const int ti0 = (g_tr & 15) << 3;
    const int tj0 = (r & 15) << 3;

    // coalesced wts staging (once for all 32 iterations)
    {
        float invs = 1.0f / sums[b];
        const float* wbase = wT + (((size_t)(b << 14) + ti0 * WW + tj0) << 5);
        for (int idx = t; idx < 512; idx += 256) {
            int p = idx >> 6, rest = idx & 63;
            float4 v = *(const float4*)(wbase + (((size_t)p * WW) << 5) + (rest << 2));
            int nl = (p << 3) + (rest >> 3);
            int c4 = (rest & 7) << 2;
            float4 sv = {v.x * invs, v.y * invs, v.z * invs, v.w * invs};
            *(float4*)&wts[nl][c4] = sv;
        }
    }

    const int s  = t & 15;
    const int g  = t >> 4;
    const int q  = g & 7;
    const int rb = g >> 3;

    // hoisted addressing: 9 staging rows / thread (12x12 halo), own-tile
    // LDS insert indices, output pixel offsets, ring classification
    int stoff[9], tidx[9];
    bool inner[9];
    #pragma unroll
    for (int n = 0; n < 9; n++) {
        int a = (n << 4) + g;
        int ar = a / 12, ac = a - ar * 12;
        inner[n] = (ar >= 2) && (ar < 10) && (ac >= 2) && (ac < 10);
        int gi = min(max(ti0 + ar - 2, 0), HH - 1);
        int gj = min(max(tj0 + ac - 2, 0), WW - 1);
        stoff[n] = (gi * WW + gj) << 7;
        tidx[n]  = a * 17 + s;
    }
    int insidx[4], outpix[4];
    #pragma unroll
    for (int k = 0; k < 4; k++) {
        int row = (rb << 2) + k;
        insidx[k] = ((2 + row) * 12 + 2 + q) * 17 + s;
        outpix[k] = (ti0 + row) * WW + (tj0 + q);
    }
    const size_t bofs = ((size_t)b << 21);
    float4 hreg[2][4];                     // own normalized tile, reg-carried

    for (int it = 0; it < 32; it++) {
        const float* hb = ((it == 0) ? hinit : ((it & 1) ? hA : hB)) + bofs;
        float* hdst = ((it & 1) ? hB : hA) + bofs;

        float4 acc[2][4];
        #pragma unroll
        for (int sl = 0; sl < 2; sl++)
            #pragma unroll
            for (int k = 0; k < 4; k++) acc[sl][k] = {0.f, 0.f, 0.f, 0.f};

        #pragma unroll
        for (int sl = 0; sl < 2; sl++) {
            if (sl) __syncthreads();       // WAR: slab0 reads done
            const int c0 = sl << 6;
            if (it == 0) {
                #pragma unroll
                for (int n = 0; n < 9; n++)
                    tile_s[tidx[n]] = *(const float4*)(hb + stoff[n] + c0 + (s << 2));
            } else {
                // ring-only global reads; own tile injected from registers
                #pragma unroll
                for (int n = 0; n < 9; n++)
                    if (!inner[n])
                        tile_s[tidx[n]] = *(const float4*)(hb + stoff[n] + c0 + (s << 2));
                #pragma unroll
                for (int k = 0; k < 4; k++)
                    tile_s[insidx[k]] = hreg[sl][k];
            }
            __syncthreads();

            #pragma unroll
            for (int dj = 0; dj < 5; dj++) {
                int ccol = q + dj;
                #pragma unroll
                for (int a = 0; a < 8; a++) {
                    int trow = (rb << 2) + a;
                    float4 v = tile_s[(trow * 12 + ccol) * 17 + s];
                    #pragma unroll
                    for (int k = 0; k < 4; k++) {
                        if (k < a - 4 || k > a) continue;   // compile-time pruned
                        int nl = (((rb << 2) + k) << 3) + q;
                        float w = wts[nl][(a - k) * 5 + dj];
                        acc[sl][k].x += w * v.x;
                        acc[sl][k].y += w * v.y;
                        acc[sl][k].z += w * v.z;
                        acc[sl][k].w += w * v.w;
                    }
                }
            }
        }

        #pragma unroll
        for (int k = 0; k < 4; k++) {
            float ss = acc[0][k].x * acc[0][k].x + acc[0][k].y * acc[0][k].y +
                       acc[0][k].z * acc[0][k].z + acc[0][k].w * acc[0][k].w +
                       acc[1][k].x * acc[1][k].x + acc[1][k].y * acc[1][k].y +
                       acc[1][k].z * acc[1][k].z + acc[1][k].w * acc[1][k].w;
            ss += __shfl_xor(ss, 1, 64);
            ss += __shfl_xor(ss, 2, 64);
            ss += __shfl_xor(ss, 4, 64);
            ss += __shfl_xor(ss, 8, 64);
            float rs = 1.0f / (sqrtf(ss) + EPSF);
            float4 r0 = {acc[0][k].x * rs, acc[0][k].y * rs, acc[0][k].z * rs, acc[0][k].w * rs};
            float4 r1 = {acc[1][k].x * rs, acc[1][k].y * rs, acc[1][k].z * rs, acc[1][k].w * rs};
            hreg[0][k] = r0;
            hreg[1][k] = r1;
            float* orow = hdst + ((size_t)outpix[k] << 7);
            *(float4*)(orow + (s << 2)) = r0;
            *(float4*)(orow + 64 + (s << 2)) = r1;
        }

        if (it != 31) {
            // --- grid barrier: release -> arrive -> spin -> acquire ---
            __threadfence();               // agent-scope release (L2 wb)
            __syncthreads();               // all block stores fenced
            if (t == 0) {
                atomicAdd(bar, 1u);        // device-scope (default on global)
                unsigned target = 512u * (unsigned)(it + 1);
                unsigned spins = 0;
                while (__hip_atomic_load(bar, __ATOMIC_ACQUIRE,
                                         __HIP_MEMORY_SCOPE_AGENT) < target) {
                    __builtin_amdgcn_s_sleep(8);
                    if (++spins > (1u << 24)) break;   // anti-hang failsafe
                }
            }
            __syncthreads();
            __threadfence();               // acquire: invalidate stale lines
        }
    }
}

// ---------------- mask head: h @ w_mask, softmax(16), transpose ----------
__global__ __launch_bounds__(256) void mask_kernel(
    const float* __restrict__ h, const float* __restrict__ wm,
    float* __restrict__ out)
{
    __shared__ float wls[QQ * MM];      // 8 KB, [c][m] native layout
    __shared__ float part[64][4][20];   // [px][slot][16m + pad]
    const int t = threadIdx.x;
    for (int idx = t; idx < QQ * MM / 4; idx += 256)
        ((float4*)wls)[idx] = ((const float4*)wm)[idx];
    const int blk = blockIdx.x;         // 512
    const int b   = blk >> 8;
    const int n0  = (blk & 255) << 6;
    const int px  = t >> 2, s = t & 3;
    const float* hr = h + (((size_t)(b << 14) + n0 + px) << 7);

    float hv[32];
    #pragma unroll
    for (int k = 0; k < 32; k++) hv[k] = hr[s + (k << 2)];
    __syncthreads();

    float4 a0 = {0,0,0,0}, a1 = a0, a2 = a0, a3 = a0;
    #pragma unroll
    for (int k = 0; k < 32; k++) {
        const float4* wrow = (const float4*)(wls + ((s + (k << 2)) << 4));
        float v = hv[k];
        float4 w0 = wrow[0], w1 = wrow[1], w2 = wrow[2], w3 = wrow[3];
        a0.x += v * w0.x; a0.y += v * w0.y; a0.z += v * w0.z; a0.w += v * w0.w;
        a1.x += v * w1.x; a1.y += v * w1.y; a1.z += v * w1.z; a1.w += v * w1.w;
        a2.x += v * w2.x; a2.y += v * w2.y; a2.z += v * w2.z; a2.w += v * w2.w;
        a3.x += v * w3.x; a3.y += v * w3.y; a3.z += v * w3.z; a3.w += v * w3.w;
    }
    *(float4*)&part[px][s][0]  = a0;
    *(float4*)&part[px][s][4]  = a1;
    *(float4*)&part[px][s][8]  = a2;
    *(float4*)&part[px][s][12] = a3;
    __syncthreads();

    float4 rr = {0,0,0,0};
    #pragma unroll
    for (int ss = 0; ss < 4; ss++) {
        float4 v = *(const float4*)&part[px][ss][s << 2];
        rr.x += v.x; rr.y += v.y; rr.z += v.z; rr.w += v.w;
    }
    float mx = fmaxf(fmaxf(rr.x, rr.y), fmaxf(rr.z, rr.w));
    mx = fmaxf(mx, __shfl_xor(mx, 1, 64));
    mx = fmaxf(mx, __shfl_xor(mx, 2, 64));
    float4 e = {expf(rr.x - mx), expf(rr.y - mx), expf(rr.z - mx), expf(rr.w - mx)};
    float ls = e.x + e.y + e.z + e.w;
    ls += __shfl_xor(ls, 1, 64);
    ls += __shfl_xor(ls, 2, 64);
    float inv = 1.0f / ls;
    float* ob = out + (((size_t)((b << 4) + (s << 2))) << 14) + n0 + px;
    ob[0]             = e.x * inv;
    ob[1 << 14]       = e.y * inv;
    ob[2 << 14]       = e.z * inv;
    ob[3 * (1 << 14)] = e.w * inv;
}

extern "C" void kernel_launch(void* const* d_in, const int* in_sizes, int n_in,
                              void* d_out, int out_size, void* d_ws, size_t ws_size,
                              hipStream_t stream)
{
    const float* x     = (const float*)d_in[0];
    // d_in[1] = edges (int32) -- unused: row/col are analytic
    const float* w1    = (const float*)d_in[2];
    const float* b1    = (const float*)d_in[3];
    const float* w2    = (const float*)d_in[4];
    const float* b2    = (const float*)d_in[5];
    const float* wk    = (const float*)d_in[6];
    const float* bk    = (const float*)d_in[7];
    const float* wq    = (const float*)d_in[8];
    const float* hinit = (const float*)d_in[9];
    const float* wm    = (const float*)d_in[10];
    float* out = (float*)d_out;

    char* ws = (char*)d_ws;
    size_t off = 0;
    auto alloc = [&](size_t bytes) -> void* {
        void* p = ws + off;
        off += (bytes + 255) & ~(size_t)255;
        return p;
    };
    float* feat1 = (float*)alloc((size_t)NBATCH * NPIX * DD * 4);
    float* feat2 = (float*)alloc((size_t)NBATCH * NPIX * DD * 4);
    float* ksb   = (float*)alloc((size_t)NBATCH * NPIX * DD * 4);
    float* qsb   = (float*)alloc((size_t)NBATCH * NPIX * DD * 4);
    float* knorm = (float*)alloc((size_t)NBATCH * NPIX * 4);
    float* qnorm = (float*)alloc((size_t)NBATCH * NPIX * 4);
    float* wT    = (float*)alloc((size_t)NBATCH * NPIX * 32 * 4);
    float* sums  = (float*)alloc(256);
    unsigned int* bar = (unsigned int*)alloc(256);
    float* hA    = (float*)alloc((size_t)NBATCH * NPIX * QQ * 4);
    float* hB    = (float*)alloc((size_t)NBATCH * NPIX * QQ * 4);

    hipMemsetAsync(sums, 0, 2 * sizeof(float), stream);
    hipMemsetAsync(bar, 0, sizeof(unsigned int), stream);

    conv1_kernel<<<512, 256, 0, stream>>>(x, w1, b1, feat1);
    conv2_kernel<<<512, 256, 0, stream>>>(feat1, w2, b2, feat2);
    kq_kernel<<<4096, 256, 0, stream>>>(feat2, wk, bk, wq, ksb, qsb, knorm, qnorm);
    edge_kernel<<<512, 256, 0, stream>>>(ksb, qsb, knorm, qnorm, wT, sums);

    // all 32 propagation iterations fused: plain launch + manual barrier
    prop_fused_kernel<<<512, 256, 0, stream>>>(hinit, hA, hB, wT, sums, bar);

    // after 32 iterations (it=31 odd) the final state is in hB
    mask_kernel<<<512, 256, 0, stream>>>(hB, wm, out);
}

// Round 4
// 504.175 us; speedup vs baseline: 10.2133x; 10.2133x over previous
//
#include <hip/hip_runtime.h>
#include <math.h>

#define HH 128
#define WW 128
#define NPIX 16384
#define CIN 3
#define DD 32
#define QQ 128
#define MM 16
#define NBATCH 2
#define EPSF 1e-8f

// ---------------- conv1: 3x3, 3->32, relu, zero-pad SAME ----------------
__global__ __launch_bounds__(256) void conv1_kernel(
    const float* __restrict__ x, const float* __restrict__ w1,
    const float* __restrict__ b1, float* __restrict__ out)
{
    __shared__ float wlds[9 * CIN * DD];
    int t = threadIdx.x;
    for (int idx = t; idx < 9 * CIN * DD / 4; idx += 256)
        ((float4*)wlds)[idx] = ((const float4*)w1)[idx];
    __syncthreads();

    int ocq = t & 3;
    int pl  = t >> 2;
    int blk = blockIdx.x;                   // 512
    int b   = blk >> 8;
    int pix = (blk & 255) * 64 + pl;
    int i = pix >> 7, j = pix & 127;
    int ocb = ocq << 3;

    float4 acc0 = *(const float4*)(b1 + ocb);
    float4 acc1 = *(const float4*)(b1 + ocb + 4);
    #pragma unroll
    for (int dy = 0; dy < 3; dy++) {
        int ii = i + dy - 1;
        if (ii < 0 || ii >= HH) continue;
        #pragma unroll
        for (int dx = 0; dx < 3; dx++) {
            int jj = j + dx - 1;
            if (jj < 0 || jj >= WW) continue;
            const float* fr = x + ((size_t)((b << 14) + ii * WW + jj)) * CIN;
            float in0 = fr[0], in1 = fr[1], in2 = fr[2];
            const float* wp = wlds + (size_t)((dy * 3 + dx) * CIN) * DD + ocb;
            #pragma unroll
            for (int ic = 0; ic < 3; ic++) {
                float inv = (ic == 0) ? in0 : (ic == 1) ? in1 : in2;
                float4 w0 = *(const float4*)(wp + ic * DD);
                float4 w1v = *(const float4*)(wp + ic * DD + 4);
                acc0.x += inv * w0.x;  acc0.y += inv * w0.y;
                acc0.z += inv * w0.z;  acc0.w += inv * w0.w;
                acc1.x += inv * w1v.x; acc1.y += inv * w1v.y;
                acc1.z += inv * w1v.z; acc1.w += inv * w1v.w;
            }
        }
    }
    float* op = out + (((size_t)(b << 14) + pix) << 5) + ocb;
    float4 r0 = {fmaxf(acc0.x, 0.f), fmaxf(acc0.y, 0.f), fmaxf(acc0.z, 0.f), fmaxf(acc0.w, 0.f)};
    float4 r1 = {fmaxf(acc1.x, 0.f), fmaxf(acc1.y, 0.f), fmaxf(acc1.z, 0.f), fmaxf(acc1.w, 0.f)};
    *(float4*)op = r0;
    *(float4*)(op + 4) = r1;
}

// ---------------- conv2: 3x3, 32->32, relu ----------------
__global__ __launch_bounds__(256) void conv2_kernel(
    const float* __restrict__ fin, const float* __restrict__ w2,
    const float* __restrict__ b2, float* __restrict__ out)
{
    __shared__ float wlds[9 * DD * DD];    // 36.9 KB
    int t = threadIdx.x;
    for (int idx = t; idx < 9 * DD * DD / 4; idx += 256)
        ((float4*)wlds)[idx] = ((const float4*)w2)[idx];
    __syncthreads();

    int ocq = t & 3;
    int pl  = t >> 2;
    int blk = blockIdx.x;                   // 512
    int b   = blk >> 8;
    int pix = (blk & 255) * 64 + pl;
    int i = pix >> 7, j = pix & 127;
    int ocb = ocq << 3;

    float4 acc0 = *(const float4*)(b2 + ocb);
    float4 acc1 = *(const float4*)(b2 + ocb + 4);
    #pragma unroll
    for (int dy = 0; dy < 3; dy++) {
        int ii = i + dy - 1;
        if (ii < 0 || ii >= HH) continue;
        #pragma unroll
        for (int dx = 0; dx < 3; dx++) {
            int jj = j + dx - 1;
            if (jj < 0 || jj >= WW) continue;
            const float* fr = fin + (((size_t)(b << 14) + ii * WW + jj)) * DD;
            float iv[DD];
            #pragma unroll
            for (int c = 0; c < DD / 4; c++)
                ((float4*)iv)[c] = *(const float4*)(fr + c * 4);
            const float* wp = wlds + (size_t)((dy * 3 + dx) * DD) * DD + ocb;
            #pragma unroll
            for (int ic = 0; ic < DD; ic++) {
                float inv = iv[ic];
                float4 w0 = *(const float4*)(wp + ic * DD);
                float4 w1v = *(const float4*)(wp + ic * DD + 4);
                acc0.x += inv * w0.x;  acc0.y += inv * w0.y;
                acc0.z += inv * w0.z;  acc0.w += inv * w0.w;
                acc1.x += inv * w1v.x; acc1.y += inv * w1v.y;
                acc1.z += inv * w1v.z; acc1.w += inv * w1v.w;
            }
        }
    }
    float* op = out + (((size_t)(b << 14) + pix) << 5) + ocb;
    float4 r0 = {fmaxf(acc0.x, 0.f), fmaxf(acc0.y, 0.f), fmaxf(acc0.z, 0.f), fmaxf(acc0.w, 0.f)};
    float4 r1 = {fmaxf(acc1.x, 0.f), fmaxf(acc1.y, 0.f), fmaxf(acc1.z, 0.f), fmaxf(acc1.w, 0.f)};
    *(float4*)op = r0;
    *(float4*)(op + 4) = r1;
}

// ---------------- k/q 1x1 projections + row norms ----------------
__global__ __launch_bounds__(256) void kq_kernel(
    const float* __restrict__ fin, const float* __restrict__ wk,
    const float* __restrict__ bk, const float* __restrict__ wq,
    float* __restrict__ ksb, float* __restrict__ qsb,
    float* __restrict__ knorm, float* __restrict__ qnorm)
{
    int g  = blockIdx.x * 256 + threadIdx.x;  // B*N*32
    int oc = g & 31;
    int bp = g >> 5;
    const float* fr = fin + (size_t)bp * DD;
    float ak = bk[oc], aq = 0.0f;
    #pragma unroll
    for (int ic = 0; ic < DD; ic += 4) {
        float4 fv = *(const float4*)(fr + ic);
        ak += fv.x * wk[(ic + 0) * DD + oc];
        ak += fv.y * wk[(ic + 1) * DD + oc];
        ak += fv.z * wk[(ic + 2) * DD + oc];
        ak += fv.w * wk[(ic + 3) * DD + oc];
        aq += fv.x * wq[(ic + 0) * DD + oc];
        aq += fv.y * wq[(ic + 1) * DD + oc];
        aq += fv.z * wq[(ic + 2) * DD + oc];
        aq += fv.w * wq[(ic + 3) * DD + oc];
    }
    ksb[g] = ak;
    qsb[g] = aq;
    float ssk = ak * ak, ssq = aq * aq;
    #pragma unroll
    for (int m = 1; m < 32; m <<= 1) {
        ssk += __shfl_xor(ssk, m, 64);
        ssq += __shfl_xor(ssq, m, 64);
    }
    if (oc == 0) {
        knorm[bp] = sqrtf(ssk);
        qnorm[bp] = sqrtf(ssq);
    }
}

// ---------------- edge scores: LDS-tiled exp(cosine) + per-batch sums ----
__global__ __launch_bounds__(256) void edge_kernel(
    const float* __restrict__ ksb, const float* __restrict__ qsb,
    const float* __restrict__ knorm, const float* __restrict__ qnorm,
    float* __restrict__ wT, float* __restrict__ sums)
{
    __shared__ float kt[144][36];   // +4 pad: breaks 32-stride bank aliasing
    __shared__ float qt[64][36];
    __shared__ float kn[144];
    __shared__ float qn[64];
    __shared__ float red[4];
    const int t   = threadIdx.x;
    const int blk = blockIdx.x;     // 512
    const int b   = blk >> 8;
    const int tl  = blk & 255;
    const int ti0 = (tl >> 4) << 3, tj0 = (tl & 15) << 3;
    const float* kb = ksb + ((size_t)b << 19);
    const float* qb = qsb + ((size_t)b << 19);

    for (int idx = t; idx < 144 * 8; idx += 256) {
        int row = idx >> 3, quad = idx & 7;
        int ar = row / 12, ac = row - ar * 12;
        int gi = min(max(ti0 + ar - 2, 0), HH - 1);
        int gj = min(max(tj0 + ac - 2, 0), WW - 1);
        *(float4*)&kt[row][quad << 2] =
            *(const float4*)(kb + ((size_t)(gi * WW + gj) << 5) + (quad << 2));
    }
    for (int idx = t; idx < 64 * 8; idx += 256) {
        int row = idx >> 3, quad = idx & 7;
        int gp = (ti0 + (row >> 3)) * WW + tj0 + (row & 7);
        *(float4*)&qt[row][quad << 2] =
            *(const float4*)(qb + ((size_t)gp << 5) + (quad << 2));
    }
    if (t < 144) {
        int ar = t / 12, ac = t - ar * 12;
        int gi = min(max(ti0 + ar - 2, 0), HH - 1);
        int gj = min(max(tj0 + ac - 2, 0), WW - 1);
        kn[t] = knorm[(b << 14) + gi * WW + gj];
    } else if (t < 208) {
        int r2 = t - 144;
        int gp = (ti0 + (r2 >> 3)) * WW + tj0 + (r2 & 7);
        qn[r2] = qnorm[(b << 14) + gp];
    }
    __syncthreads();

    const int nl = t >> 2, s = t & 3;
    const int p = nl >> 3, q = nl & 7;
    float4 qv[8];
    #pragma unroll
    for (int c = 0; c < 8; c++) qv[c] = *(const float4*)&qt[nl][c << 2];
    const float qnv = qn[nl];
    const int gp = (ti0 + p) * WW + tj0 + q;
    float* wrow = wT + (((size_t)(b << 14) + gp) << 5);
    float lsum = 0.0f;
    for (int o = s; o < 25; o += 4) {
        int di = o / 5, dj = o - di * 5;      // 0..4
        int krow = (p + di) * 12 + (q + dj);  // halo coords
        const float* kr = &kt[krow][0];
        float dot = 0.0f;
        #pragma unroll
        for (int c = 0; c < 8; c++) {
            float4 kv = *(const float4*)(kr + (c << 2));
            dot += qv[c].x * kv.x + qv[c].y * kv.y + qv[c].z * kv.z + qv[c].w * kv.w;
        }
        float den = fmaxf(qnv * kn[krow], EPSF);
        float es = expf(dot / den);   // cosine in [-1,1]: no max-sub needed
        wrow[o] = es;
        lsum += es;
    }
    #pragma unroll
    for (int mm = 1; mm < 64; mm <<= 1) lsum += __shfl_xor(lsum, mm, 64);
    if ((t & 63) == 0) red[t >> 6] = lsum;
    __syncthreads();
    if (t == 0) atomicAdd(&sums[b], red[0] + red[1] + red[2] + red[3]);
}

// ---------------- one propagation iteration: half-tile px-split ----------
// 1024 blocks: half-tile = 4 rows x 8 cols x 128 ch. LDS ~31 KB and
// <=128 VGPR -> 4 blocks/CU = 16 waves/CU (50% occupancy) vs 2 blocks/CU
// at the 512-block 8x8 tiling: doubles latency hiding on the global
// staging loads that dominate per-iteration time (working set is
// L2/L3-resident, so this is latency- not BW-bound).
// XCD slab: blk&7 -> XCD owns 8 contiguous half-tile-rows (L2-local).
__global__ __launch_bounds__(256, 4) void prop_kernel(
    const float* __restrict__ hin, float* __restrict__ hout,
    const float* __restrict__ wT, const float* __restrict__ sums)
{
    __shared__ float4 tile_s[96 * 17];   // 8x12 halo px x 16 c-slots, pad 17
    __shared__ float wts[32][36];        // own 32 px, pre-scaled weights
    const int t = threadIdx.x;
    const int x = blockIdx.x & 7;        // XCD slab
    const int r = blockIdx.x >> 3;       // 0..127 within slab
    const int g_hr = (x << 3) + (r >> 4);// global half-tile-row 0..63
    const int tcol = r & 15;
    const int b    = g_hr >> 5;
    const int rem  = g_hr & 31;
    const int ti0h = ((rem >> 1) << 3) + ((rem & 1) << 2);  // half-tile row0
    const int tj0  = tcol << 3;

    // wts staging: exactly one float4 per thread (32 px x 8 quads)
    {
        float invs = 1.0f / sums[b];
        const float* wbase = wT + (((size_t)(b << 14) + ti0h * WW + tj0) << 5);
        int p = t >> 6, rest = t & 63;   // p = row 0..3
        float4 v = *(const float4*)(wbase + (((size_t)p * WW) << 5) + (rest << 2));
        int nl = (p << 3) + (rest >> 3);
        int c4 = (rest & 7) << 2;
        float4 sv = {v.x * invs, v.y * invs, v.z * invs, v.w * invs};
        *(float4*)&wts[nl][c4] = sv;
    }

    const int s  = t & 15;               // channel slot
    const int g  = t >> 4;               // 0..15
    const int q  = g & 7;                // col within half-tile
    const int rp = g >> 3;               // row-pair 0/1

    // hoisted halo addressing: 6 staging rows / thread (8x12 halo)
    int stoff[6], tidx[6];
    #pragma unroll
    for (int n = 0; n < 6; n++) {
        int a = (n << 4) + g;            // 0..95
        int ar = a / 12, ac = a - ar * 12;
        int gi = min(max(ti0h + ar - 2, 0), HH - 1);
        int gj = min(max(tj0 + ac - 2, 0), WW - 1);
        stoff[n] = (gi * WW + gj) << 7;
        tidx[n]  = a * 17 + s;
    }
    const float* hb = hin + ((size_t)b << 21);

    float4 acc[2][2];
    #pragma unroll
    for (int sl = 0; sl < 2; sl++)
        #pragma unroll
        for (int k = 0; k < 2; k++) acc[sl][k] = {0.f, 0.f, 0.f, 0.f};

    #pragma unroll
    for (int sl = 0; sl < 2; sl++) {
        if (sl) __syncthreads();         // WAR: slab0 reads done
        const int c0 = sl << 6;
        #pragma unroll
        for (int n = 0; n < 6; n++)
            tile_s[tidx[n]] = *(const float4*)(hb + stoff[n] + c0 + (s << 2));
        __syncthreads();

        #pragma unroll
        for (int dj = 0; dj < 5; dj++) {
            int ccol = q + dj;
            #pragma unroll
            for (int a = 0; a < 6; a++) {
                float4 v = tile_s[(((rp << 1) + a) * 12 + ccol) * 17 + s];
                #pragma unroll
                for (int k = 0; k < 2; k++) {
                    if (k < a - 4 || k > a) continue;   // compile-time pruned
                    float w = wts[(((rp << 1) + k) << 3) + q][(a - k) * 5 + dj];
                    acc[sl][k].x += w * v.x;
                    acc[sl][k].y += w * v.y;
                    acc[sl][k].z += w * v.z;
                    acc[sl][k].w += w * v.w;
                }
            }
        }
    }

    #pragma unroll
    for (int k = 0; k < 2; k++) {
        float ss = acc[0][k].x * acc[0][k].x + acc[0][k].y * acc[0][k].y +
                   acc[0][k].z * acc[0][k].z + acc[0][k].w * acc[0][k].w +
                   acc[1][k].x * acc[1][k].x + acc[1][k].y * acc[1][k].y +
                   acc[1][k].z * acc[1][k].z + acc[1][k].w * acc[1][k].w;
        ss += __shfl_xor(ss, 1, 64);
        ss += __shfl_xor(ss, 2, 64);
        ss += __shfl_xor(ss, 4, 64);
        ss += __shfl_xor(ss, 8, 64);
        float rs = 1.0f / (sqrtf(ss) + EPSF);
        int gp = (ti0h + (rp << 1) + k) * WW + (tj0 + q);
        float* orow = hout + (((size_t)(b << 14) + gp) << 7);
        float4 r0 = {acc[0][k].x * rs, acc[0][k].y * rs, acc[0][k].z * rs, acc[0][k].w * rs};
        float4 r1 = {acc[1][k].x * rs, acc[1][k].y * rs, acc[1][k].z * rs, acc[1][k].w * rs};
        *(float4*)(orow + (s << 2)) = r0;
        *(float4*)(orow + 64 + (s << 2)) = r1;
    }
}

// ---------------- mask head: h @ w_mask, softmax(16), transpose ----------
__global__ __launch_bounds__(256) void mask_kernel(
    const float* __restrict__ h, const float* __restrict__ wm,
    float* __restrict__ out)
{
    __shared__ float wls[QQ * MM];      // 8 KB, [c][m] native layout
    __shared__ float part[64][4][20];   // [px][slot][16m + pad]
    const int t = threadIdx.x;
    for (int idx = t; idx < QQ * MM / 4; idx += 256)
        ((float4*)wls)[idx] = ((const float4*)wm)[idx];
    const int blk = blockIdx.x;         // 512
    const int b   = blk >> 8;
    const int n0  = (blk & 255) << 6;
    const int px  = t >> 2, s = t & 3;
    const float* hr = h + (((size_t)(b << 14) + n0 + px) << 7);

    float hv[32];
    #pragma unroll
    for (int k = 0; k < 32; k++) hv[k] = hr[s + (k << 2)];
    __syncthreads();

    float4 a0 = {0,0,0,0}, a1 = a0, a2 = a0, a3 = a0;
    #pragma unroll
    for (int k = 0; k < 32; k++) {
        const float4* wrow = (const float4*)(wls + ((s + (k << 2)) << 4));
        float v = hv[k];
        float4 w0 = wrow[0], w1 = wrow[1], w2 = wrow[2], w3 = wrow[3];
        a0.x += v * w0.x; a0.y += v * w0.y; a0.z += v * w0.z; a0.w += v * w0.w;
        a1.x += v * w1.x; a1.y += v * w1.y; a1.z += v * w1.z; a1.w += v * w1.w;
        a2.x += v * w2.x; a2.y += v * w2.y; a2.z += v * w2.z; a2.w += v * w2.w;
        a3.x += v * w3.x; a3.y += v * w3.y; a3.z += v * w3.z; a3.w += v * w3.w;
    }
    *(float4*)&part[px][s][0]  = a0;
    *(float4*)&part[px][s][4]  = a1;
    *(float4*)&part[px][s][8]  = a2;
    *(float4*)&part[px][s][12] = a3;
    __syncthreads();

    float4 rr = {0,0,0,0};
    #pragma unroll
    for (int ss = 0; ss < 4; ss++) {
        float4 v = *(const float4*)&part[px][ss][s << 2];
        rr.x += v.x; rr.y += v.y; rr.z += v.z; rr.w += v.w;
    }
    float mx = fmaxf(fmaxf(rr.x, rr.y), fmaxf(rr.z, rr.w));
    mx = fmaxf(mx, __shfl_xor(mx, 1, 64));
    mx = fmaxf(mx, __shfl_xor(mx, 2, 64));
    float4 e = {expf(rr.x - mx), expf(rr.y - mx), expf(rr.z - mx), expf(rr.w - mx)};
    float ls = e.x + e.y + e.z + e.w;
    ls += __shfl_xor(ls, 1, 64);
    ls += __shfl_xor(ls, 2, 64);
    float inv = 1.0f / ls;
    float* ob = out + (((size_t)((b << 4) + (s << 2))) << 14) + n0 + px;
    ob[0]             = e.x * inv;
    ob[1 << 14]       = e.y * inv;
    ob[2 << 14]       = e.z * inv;
    ob[3 * (1 << 14)] = e.w * inv;
}

extern "C" void kernel_launch(void* const* d_in, const int* in_sizes, int n_in,
                              void* d_out, int out_size, void* d_ws, size_t ws_size,
                              hipStream_t stream)
{
    const float* x     = (const float*)d_in[0];
    // d_in[1] = edges (int32) -- unused: row/col are analytic
    const float* w1    = (const float*)d_in[2];
    const float* b1    = (const float*)d_in[3];
    const float* w2    = (const float*)d_in[4];
    const float* b2    = (const float*)d_in[5];
    const float* wk    = (const float*)d_in[6];
    const float* bk    = (const float*)d_in[7];
    const float* wq    = (const float*)d_in[8];
    const float* hinit = (const float*)d_in[9];
    const float* wm    = (const float*)d_in[10];
    float* out = (float*)d_out;

    char* ws = (char*)d_ws;
    size_t off = 0;
    auto alloc = [&](size_t bytes) -> void* {
        void* p = ws + off;
        off += (bytes + 255) & ~(size_t)255;
        return p;
    };
    float* feat1 = (float*)alloc((size_t)NBATCH * NPIX * DD * 4);
    float* feat2 = (float*)alloc((size_t)NBATCH * NPIX * DD * 4);
    float* ksb   = (float*)alloc((size_t)NBATCH * NPIX * DD * 4);
    float* qsb   = (float*)alloc((size_t)NBATCH * NPIX * DD * 4);
    float* knorm = (float*)alloc((size_t)NBATCH * NPIX * 4);
    float* qnorm = (float*)alloc((size_t)NBATCH * NPIX * 4);
    float* wT    = (float*)alloc((size_t)NBATCH * NPIX * 32 * 4);
    float* sums  = (float*)alloc(256);
    float* hA    = (float*)alloc((size_t)NBATCH * NPIX * QQ * 4);
    float* hB    = (float*)alloc((size_t)NBATCH * NPIX * QQ * 4);

    hipMemsetAsync(sums, 0, 2 * sizeof(float), stream);

    conv1_kernel<<<512, 256, 0, stream>>>(x, w1, b1, feat1);
    conv2_kernel<<<512, 256, 0, stream>>>(feat1, w2, b2, feat2);
    kq_kernel<<<4096, 256, 0, stream>>>(feat2, wk, bk, wq, ksb, qsb, knorm, qnorm);
    edge_kernel<<<512, 256, 0, stream>>>(ksb, qsb, knorm, qnorm, wT, sums);

    const float* src = hinit;
    float* dst = hA;
    for (int it = 0; it < 32; it++) {
        prop_kernel<<<1024, 256, 0, stream>>>(src, dst, wT, sums);
        src = dst;
        dst = (dst == hA) ? hB : hA;
    }
    mask_kernel<<<512, 256, 0, stream>>>(src, wm, out);
}